// Round 8
// baseline (270.308 us; speedup 1.0000x reference)
//
#include <hip/hip_runtime.h>
#include <hip/hip_bf16.h>
#include <math.h>

typedef __attribute__((ext_vector_type(8))) short bf16x8;
typedef __attribute__((ext_vector_type(4))) float f32x4;
typedef __attribute__((ext_vector_type(16))) float f32x16;

constexpr int Bc   = 2;
constexpr int Lc   = 2048;
constexpr int HIDc = 1024;
constexpr int Hc   = 16;
constexpr int HDc  = 64;
constexpr int Mc   = 4096;

__device__ __forceinline__ ushort f2bf(float f) {
  uint u = __float_as_uint(f);
  u += 0x7fff + ((u >> 16) & 1);   // RNE
  return (ushort)(u >> 16);
}

__device__ __forceinline__ void gload16(const ushort* g, ushort* l) {
  __builtin_amdgcn_global_load_lds(
      (const __attribute__((address_space(1))) uint*)(const void*)g,
      (__attribute__((address_space(3))) uint*)(void*)l, 16, 0, 0);
}

__device__ __forceinline__ uint cvtpk(float lo, float hi_) {
  uint r;
  asm("v_cvt_pk_bf16_f32 %0, %1, %2" : "=v"(r) : "v"(lo), "v"(hi_));
  return r;
}
__device__ __forceinline__ void pswap(uint &a, uint &b) {
  asm("v_permlane32_swap_b32 %0, %1" : "+v"(a), "+v"(b));
}

// ---------------------------------------------------------------------------
// GEMM core: C[M=4096,N=1024] = A[fp32] @ B[fp32,N-major]^T + bias.
// Tile 64(M) x 128(N), BK=32, 8 waves (2M x 4N), double-buffered LDS.
// A and B converted fp32->bf16 during reg-staging (per-lane ds_write, immune
// to the global_load_lds wave-exec hazard). XOR chunk swizzle write+read.
// MODE 0: fp32 row-major; 1: bf16 [bh][q][d]; 2: bf16 [bh][d][k].
// ---------------------------------------------------------------------------
template<int MODE>
__device__ __forceinline__ void gemm_core(
    const float* __restrict__ A, const float* __restrict__ Bw,
    const float* __restrict__ bias, float* __restrict__ Cf,
    ushort* __restrict__ Cb, int tile,
    ushort (*As)[2048], ushort (*Bs)[4096])
{
  const int tid  = threadIdx.x;
  const int lane = tid & 63;
  const int w    = tid >> 6;
  const int g    = lane >> 4;
  const int lc   = lane & 15;
  const int wr   = w >> 2;      // 0..1 (M)
  const int wc   = w & 3;       // 0..3 (N)
  const int row0 = (tile >> 3) * 64;
  const int col0 = (tile & 7) * 128;

  // staging slots: B 128 rows x 4 chunks (all 512 thr); A 64 x 4 (tid<256)
  const int sr  = tid >> 2;
  const int sc_ = tid & 3;
  const int wofs = sr*32 + (sc_ ^ ((sr >> 1) & 3))*8;   // shorts
  const float* pA = A  + (size_t)(row0 + sr) * HIDc + sc_*8;  // valid tid<256
  const float* pB = Bw + (size_t)(col0 + sr) * HIDc + sc_*8;

  int aoff[2], boff[2];
  #pragma unroll
  for (int mi = 0; mi < 2; ++mi) {
    int r = wr*32 + mi*16 + lc;
    aoff[mi] = r*32 + (g ^ ((r >> 1) & 3)) * 8;
  }
  #pragma unroll
  for (int ni = 0; ni < 2; ++ni) {
    int r = wc*32 + ni*16 + lc;
    boff[ni] = r*32 + (g ^ ((r >> 1) & 3)) * 8;
  }

  f32x4 acc[2][2];
  #pragma unroll
  for (int mi = 0; mi < 2; ++mi)
    #pragma unroll
    for (int ni = 0; ni < 2; ++ni) acc[mi][ni] = (f32x4){0.f,0.f,0.f,0.f};

  float4 a0, a1, b0, b1;
  auto ld = [&](int ko) {
    b0 = *(const float4*)(pB + ko);
    b1 = *(const float4*)(pB + ko + 4);
    if (tid < 256) {
      a0 = *(const float4*)(pA + ko);
      a1 = *(const float4*)(pA + ko + 4);
    }
  };
  auto wrbuf = [&](int bi) {
    ushort tb[8] = { f2bf(b0.x), f2bf(b0.y), f2bf(b0.z), f2bf(b0.w),
                     f2bf(b1.x), f2bf(b1.y), f2bf(b1.z), f2bf(b1.w) };
    *(uint4*)&Bs[bi][wofs] = *(uint4*)tb;
    if (tid < 256) {
      ushort ta[8] = { f2bf(a0.x), f2bf(a0.y), f2bf(a0.z), f2bf(a0.w),
                       f2bf(a1.x), f2bf(a1.y), f2bf(a1.z), f2bf(a1.w) };
      *(uint4*)&As[bi][wofs] = *(uint4*)ta;
    }
  };

  ld(0); wrbuf(0);
  __syncthreads();

  for (int t = 0; t < 32; ++t) {
    if (t < 31) ld((t + 1) * 32);
    const ushort* as = As[t & 1];
    const ushort* bs = Bs[t & 1];
    bf16x8 af[2], bfr[2];
    #pragma unroll
    for (int mi = 0; mi < 2; ++mi) af[mi] = *(const bf16x8*)&as[aoff[mi]];
    #pragma unroll
    for (int ni = 0; ni < 2; ++ni) bfr[ni] = *(const bf16x8*)&bs[boff[ni]];
    #pragma unroll
    for (int mi = 0; mi < 2; ++mi)
      #pragma unroll
      for (int ni = 0; ni < 2; ++ni)
        acc[mi][ni] = __builtin_amdgcn_mfma_f32_16x16x32_bf16(af[mi], bfr[ni], acc[mi][ni], 0, 0, 0);
    if (t < 31) wrbuf((t + 1) & 1);
    __syncthreads();
  }

  const int colbase = col0 + wc*32;
  if (MODE == 0) {
    #pragma unroll
    for (int mi = 0; mi < 2; ++mi) {
      int row = row0 + wr*32 + mi*16 + 4*g;
      #pragma unroll
      for (int ni = 0; ni < 2; ++ni) {
        int col = colbase + ni*16 + lc;
        float bb = bias[col];
        #pragma unroll
        for (int reg = 0; reg < 4; ++reg)
          Cf[(size_t)(row + reg) * HIDc + col] = acc[mi][ni][reg] + bb;
      }
    }
  } else if (MODE == 1) {
    #pragma unroll
    for (int mi = 0; mi < 2; ++mi) {
      int row = row0 + wr*32 + mi*16 + 4*g;
      int b = row >> 11, qq = row & 2047;
      #pragma unroll
      for (int ni = 0; ni < 2; ++ni) {
        int col = colbase + ni*16 + lc;
        int h = col >> 6, d = col & 63;
        float bb = bias[col];
        size_t base = (((size_t)b*Hc + h)*Lc + qq)*HDc + d;
        #pragma unroll
        for (int reg = 0; reg < 4; ++reg)
          Cb[base + (size_t)reg*HDc] = f2bf(acc[mi][ni][reg] + bb);
      }
    }
  } else {
    #pragma unroll
    for (int mi = 0; mi < 2; ++mi) {
      int row = row0 + wr*32 + mi*16 + 4*g;
      int b = row >> 11, kk = row & 2047;
      #pragma unroll
      for (int ni = 0; ni < 2; ++ni) {
        int col = colbase + ni*16 + lc;
        int h = col >> 6, d = col & 63;
        float bb = bias[col];
        ushort t4[4];
        #pragma unroll
        for (int reg = 0; reg < 4; ++reg) t4[reg] = f2bf(acc[mi][ni][reg] + bb);
        *(uint2*)&Cb[(((size_t)b*Hc + h)*HDc + d)*Lc + kk] = *(uint2*)t4;
      }
    }
  }
}

__global__ __launch_bounds__(512)
void gemm_fused(const float* __restrict__ q, const float* __restrict__ k,
                const float* __restrict__ v,
                const float* __restrict__ Wq, const float* __restrict__ Wk,
                const float* __restrict__ Wv,
                const float* __restrict__ bq, const float* __restrict__ bk,
                const float* __restrict__ bv,
                ushort* Qc, ushort* Kc, ushort* Vt)
{
  __shared__ ushort As[2][2048];
  __shared__ ushort Bs[2][4096];
  int gi   = blockIdx.x >> 9;
  int tile = blockIdx.x & 511;
  if (gi == 0)      gemm_core<1>(q, Wq, bq, nullptr, Qc, tile, As, Bs);
  else if (gi == 1) gemm_core<1>(k, Wk, bk, nullptr, Kc, tile, As, Bs);
  else              gemm_core<2>(v, Wv, bv, nullptr, Vt, tile, As, Bs);
}

__global__ __launch_bounds__(512)
void gemm_out(const float* __restrict__ X, const float* __restrict__ Wo,
              const float* __restrict__ bo, float* __restrict__ out)
{
  __shared__ ushort As[2][2048];
  __shared__ ushort Bs[2][4096];
  gemm_core<0>(X, Wo, bo, out, nullptr, blockIdx.x, As, Bs);
}

// ---------------------------------------------------------------------------
// Swapped-QK^T 32x32 MFMA flash attention with Shaw relative positions.
// KVBLK=32, 2 waves/block (QBLK=64), LDS 18.0 KB -> 8 blocks/CU.
// *** Every global_load_lds is issued under FULL-wave exec: staging work is
// selected by the wave-uniform index widx = seg*2 + w only (R5's proven
// pattern). R6/R7 failed because partial-exec gloads corrupted the other
// double-buffer's V rows (LDS-write side does not follow exec). ***
// Per buffer: V [64 d][pitch 40] = 320 chunks (ch4 = pad), then K
// [32 k][pitch 64] = 256 chunks with XOR chunk swizzle (physical chunk =
// logical ^ (row&7)) applied on the global SOURCE and on the ds_read —
// both-sides rule, since gload_lds writes linearly. No K pad -> no OOB;
// buffer is exactly 4608 shorts, overrun impossible.
// Single 32-k group per tile; exp2-folded softmax (no max; scores bounded);
// Shaw region sums per-lane; P->A-operand via cvt_pk + permlane32_swap;
// epilogue per-q scalars broadcast via __shfl. X written fp32.
// ---------------------------------------------------------------------------
__global__ __launch_bounds__(128, 4)
void attn_mfma32(const ushort* __restrict__ Qc, const ushort* __restrict__ Kc,
                 const ushort* __restrict__ Vt, const float* __restrict__ relk,
                 const float* __restrict__ relv, float* __restrict__ X)
{
  __shared__ ushort KVs[2][4608];      // per buf: V 64x40 | K 32x64(swz)

  const int tid  = threadIdx.x;
  const int w    = tid >> 6;
  const int lane = tid & 63;
  const int lq   = lane & 31;
  const int hi   = lane >> 5;

  // XCD swizzle (1024 blocks = 8 x 128)
  const int swz  = (blockIdx.x & 7) * 128 + (blockIdx.x >> 3);
  const int qblk = swz & 31;
  const int bh   = swz >> 5;
  const int b    = bh >> 4;
  const int h    = bh & 15;
  const int qw   = qblk*64 + w*32;
  const int qabs = qw + lq;

  constexpr float C2 = 0.72134752f;    // 0.5 * log2(e)

  const ushort* Kbh = Kc + (size_t)bh*Lc*HDc;
  const ushort* Vbh = Vt + (size_t)bh*HDc*Lc;

  // Q B-fragments (col=q=lq), k-slice d = 16s + 8hi + j
  bf16x8 qf[4];
  const ushort* qbase = Qc + ((size_t)bh*Lc + qabs)*HDc + 8*hi;
  #pragma unroll
  for (int s = 0; s < 4; ++s) qf[s] = *(const bf16x8*)(qbase + 16*s);

  // dq[bucket] = Q . relk[bucket] via one 32x32 mfma chain (A=relk rows)
  f32x16 dc;
  #pragma unroll
  for (int i = 0; i < 16; ++i) dc[i] = 0.f;
  #pragma unroll
  for (int s = 0; s < 4; ++s) {
    union { ushort u[8]; bf16x8 v; } rf;
    #pragma unroll
    for (int j = 0; j < 8; ++j) rf.u[j] = 0;
    if (lq < 5) {
      #pragma unroll
      for (int j = 0; j < 8; ++j) rf.u[j] = f2bf(relk[lq*HDc + 16*s + 8*hi + j]);
    }
    dc = __builtin_amdgcn_mfma_f32_32x32x16_bf16(rf.v, qf[s], dc, 0, 0, 0);
  }
  float o0 = __shfl_xor(dc[0], 32), o1 = __shfl_xor(dc[1], 32),
        o2 = __shfl_xor(dc[2], 32), o3 = __shfl_xor(dc[3], 32);
  float dqh0, dqh1, dqh2, dqh3, dqh4;
  if (hi == 0) { dqh0 = dc[0]; dqh1 = dc[1]; dqh2 = dc[2]; dqh3 = dc[3]; dqh4 = o0; }
  else         { dqh0 = o0;    dqh1 = o1;    dqh2 = o2;    dqh3 = o3;    dqh4 = dc[0]; }
  dqh0 *= C2; dqh1 *= C2; dqh2 *= C2; dqh3 *= C2; dqh4 *= C2;

  f32x16 acc0, acc1;
  #pragma unroll
  for (int i = 0; i < 16; ++i) { acc0[i] = 0.f; acc1[i] = 0.f; }
  float lsum = 0.f, llo = 0.f, e1 = 0.f, e2 = 0.f, e3 = 0.f;

  // stage one 32-k tile; 9 full-wave loads selected by wave-uniform widx.
  // V chunk vc: row=vc/5 (d), ch=vc%5 (ch4=pad reads next-k, in-bounds of ws).
  // K chunk kc: row=kc>>3 (k), physical chunk pch=kc&7 holds global chunk
  // pch^(row&7); LDS dest linear at (320+kc)*8 shorts.
  auto stage = [&](ushort* dst, int k0) {
    #pragma unroll
    for (int seg = 0; seg < 5; ++seg) {
      int widx = seg*2 + w;             // wave-uniform 0..9
      if (widx < 5) {
        int vc = widx*64 + lane;
        int row = vc/5, ch = vc - row*5;
        gload16(Vbh + (size_t)row*Lc + k0 + ch*8, dst + vc*8);
      } else if (widx < 9) {
        int kc = (widx - 5)*64 + lane;
        int row = kc >> 3, pch = kc & 7;
        int gch = pch ^ (row & 7);
        gload16(Kbh + (size_t)(k0 + row)*HDc + gch*8, dst + (320 + kc)*8);
      }
    }
  };

  stage(KVs[0], 0);
  __syncthreads();

  for (int t = 0; t < Lc/32; ++t) {
    const ushort* vb_ = KVs[t & 1];
    const ushort* kb_ = vb_ + 2560;
    if (t + 1 < Lc/32) stage(KVs[(t+1) & 1], (t+1)*32);
    const int kb = t*32;

    // K fragments (swizzled read), QK^T (C rows = k, cols = q)
    bf16x8 kfa[4];
    #pragma unroll
    for (int s = 0; s < 4; ++s)
      kfa[s] = *(const bf16x8*)&kb_[lq*64 + ((2*s + hi) ^ (lq & 7))*8];
    f32x16 c0;
    #pragma unroll
    for (int i = 0; i < 16; ++i) c0[i] = 0.f;
    __builtin_amdgcn_s_setprio(1);
    #pragma unroll
    for (int s = 0; s < 4; ++s)
      c0 = __builtin_amdgcn_mfma_f32_32x32x16_bf16(kfa[s], qf[s], c0, 0, 0, 0);
    __builtin_amdgcn_s_setprio(0);

    // V fragments (B operand: col=d, k elements)
    bf16x8 vf00 = *(const bf16x8*)&vb_[lq*40      + hi*8];
    bf16x8 vf01 = *(const bf16x8*)&vb_[(32+lq)*40 + hi*8];
    bf16x8 vf10 = *(const bf16x8*)&vb_[lq*40      + (2+hi)*8];
    bf16x8 vf11 = *(const bf16x8*)&vb_[(32+lq)*40 + (2+hi)*8];

    // softmax (no max subtraction; scores bounded), region sums, pack
    uint pk[8];
    const bool allhi = (kb >= qw + 33);
    const bool alllo = (kb + 33 <= qw);
    if (allhi | alllo) {
      const float dq = allhi ? dqh4 : dqh0;
      float gs = 0.f;
      #pragma unroll
      for (int jj = 0; jj < 8; ++jj) {
        float pa = __builtin_amdgcn_exp2f(__builtin_fmaf(c0[2*jj],   C2, dq));
        float pb = __builtin_amdgcn_exp2f(__builtin_fmaf(c0[2*jj+1], C2, dq));
        gs += pa + pb;
        pk[jj] = cvtpk(pa, pb);
      }
      lsum += gs;
      if (alllo) llo += gs;
    } else {
      int bnum = kb + 4*hi - qabs;
      #pragma unroll
      for (int jj = 0; jj < 8; ++jj) {
        int r0 = 2*jj;
        int d0 = bnum + ((r0 & 3) + 8*(r0 >> 2));
        int d1 = d0 + 1;
        float dqa = d0 <= -2 ? dqh0 : (d0 >= 2 ? dqh4 :
                    (d0 == -1 ? dqh1 : (d0 == 0 ? dqh2 : dqh3)));
        float dqb = d1 <= -2 ? dqh0 : (d1 >= 2 ? dqh4 :
                    (d1 == -1 ? dqh1 : (d1 == 0 ? dqh2 : dqh3)));
        float pa = __builtin_amdgcn_exp2f(__builtin_fmaf(c0[r0],   C2, dqa));
        float pb = __builtin_amdgcn_exp2f(__builtin_fmaf(c0[r0+1], C2, dqb));
        lsum += pa + pb;
        llo += (d0 <= -2 ? pa : 0.f) + (d1 <= -2 ? pb : 0.f);
        e1  += (d0 == -1 ? pa : 0.f) + (d1 == -1 ? pb : 0.f);
        e2  += (d0 ==  0 ? pa : 0.f) + (d1 ==  0 ? pb : 0.f);
        e3  += (d0 ==  1 ? pa : 0.f) + (d1 ==  1 ? pb : 0.f);
        pk[jj] = cvtpk(pa, pb);
      }
    }

    // PV (A = P via permlane redistribution)
    uint X0 = pk[0], X1 = pk[1], Y0 = pk[2], Y1 = pk[3];
    pswap(X0, Y0); pswap(X1, Y1);
    union { uint u[4]; bf16x8 v; } aw0;
    aw0.u[0] = X0; aw0.u[1] = X1; aw0.u[2] = Y0; aw0.u[3] = Y1;
    X0 = pk[4]; X1 = pk[5]; Y0 = pk[6]; Y1 = pk[7];
    pswap(X0, Y0); pswap(X1, Y1);
    union { uint u[4]; bf16x8 v; } aw1;
    aw1.u[0] = X0; aw1.u[1] = X1; aw1.u[2] = Y0; aw1.u[3] = Y1;
    __builtin_amdgcn_s_setprio(1);
    acc0 = __builtin_amdgcn_mfma_f32_32x32x16_bf16(aw0.v, vf00, acc0, 0, 0, 0);
    acc1 = __builtin_amdgcn_mfma_f32_32x32x16_bf16(aw0.v, vf01, acc1, 0, 0, 0);
    acc0 = __builtin_amdgcn_mfma_f32_32x32x16_bf16(aw1.v, vf10, acc0, 0, 0, 0);
    acc1 = __builtin_amdgcn_mfma_f32_32x32x16_bf16(aw1.v, vf11, acc1, 0, 0, 0);
    __builtin_amdgcn_s_setprio(0);
    __syncthreads();
  }

  // epilogue: combine hi-halves (all sums linear), shfl-broadcast per-q scalars
  float Ls = lsum + __shfl_xor(lsum, 32);
  float Lo = llo  + __shfl_xor(llo, 32);
  float E1 = e1   + __shfl_xor(e1, 32);
  float E2 = e2   + __shfl_xor(e2, 32);
  float E3 = e3   + __shfl_xor(e3, 32);
  float inv = 1.f / Ls;
  float s0v = Lo*inv, s1v = E1*inv, s2v = E2*inv, s3v = E3*inv;
  float s4v = 1.f - s0v - s1v - s2v - s3v;

  float rvv[5][2];
  #pragma unroll
  for (int r = 0; r < 5; ++r) {
    rvv[r][0] = relv[r*HDc + lq];
    rvv[r][1] = relv[r*HDc + 32 + lq];
  }
  #pragma unroll
  for (int r = 0; r < 16; ++r) {
    int qloc = ((r & 3) + 8*(r >> 2)) + 4*hi;
    float iv = __shfl(inv, qloc);
    float t0 = __shfl(s0v, qloc);
    float t1 = __shfl(s1v, qloc);
    float t2 = __shfl(s2v, qloc);
    float t3 = __shfl(s3v, qloc);
    float t4 = __shfl(s4v, qloc);
    size_t rowb = ((size_t)(b*Lc + qw + qloc))*HIDc + h*HDc;
    X[rowb + lq]      = acc0[r]*iv + t0*rvv[0][0] + t1*rvv[1][0] + t2*rvv[2][0]
                      + t3*rvv[3][0] + t4*rvv[4][0];
    X[rowb + 32 + lq] = acc1[r]*iv + t0*rvv[0][1] + t1*rvv[1][1] + t2*rvv[2][1]
                      + t3*rvv[3][1] + t4*rvv[4][1];
  }
}

// ---------------------------------------------------------------------------
extern "C" void kernel_launch(void* const* d_in, const int* in_sizes, int n_in,
                              void* d_out, int out_size, void* d_ws, size_t ws_size,
                              hipStream_t stream) {
  const float* query = (const float*)d_in[0];
  const float* key   = (const float*)d_in[1];
  const float* value = (const float*)d_in[2];
  const float* Wq    = (const float*)d_in[3];
  const float* bq    = (const float*)d_in[4];
  const float* Wk    = (const float*)d_in[5];
  const float* bk    = (const float*)d_in[6];
  const float* Wv    = (const float*)d_in[7];
  const float* bv    = (const float*)d_in[8];
  const float* Wo    = (const float*)d_in[9];
  const float* bo    = (const float*)d_in[10];
  const float* relk  = (const float*)d_in[11];
  const float* relv  = (const float*)d_in[12];
  float* out = (float*)d_out;

  // ws: Qc, Kc, Vt (bf16, 8.39 MB each) then X (fp32, 16.78 MB) = 41.9 MB.
  // V pad-chunk reads may run a few elements past Vt (into Xb) - in-bounds.
  size_t S = (size_t)Bc * Hc * Lc * HDc;   // 4.19M elems
  ushort* Qc = (ushort*)d_ws;
  ushort* Kc = Qc + S;
  ushort* Vt = Kc + S;
  float*  Xb = (float*)(Vt + S);

  gemm_fused<<<3*512, 512, 0, stream>>>(query, key, value, Wq, Wk, Wv,
                                        bq, bk, bv, Qc, Kc, Vt);

  attn_mfma32<<<Bc * Hc * (Lc / 64), 128, 0, stream>>>(Qc, Kc, Vt, relk, relv, Xb);

  gemm_out<<<512, 512, 0, stream>>>(Xb, Wo, bo, out);
}

// Round 9
// 178.386 us; speedup vs baseline: 1.5153x; 1.5153x over previous
//
#include <hip/hip_runtime.h>
#include <hip/hip_bf16.h>
#include <math.h>

typedef __attribute__((ext_vector_type(8))) short bf16x8;
typedef __attribute__((ext_vector_type(4))) float f32x4;
typedef __attribute__((ext_vector_type(16))) float f32x16;

constexpr int Bc   = 2;
constexpr int Lc   = 2048;
constexpr int HIDc = 1024;
constexpr int Hc   = 16;
constexpr int HDc  = 64;
constexpr int Mc   = 4096;

__device__ __forceinline__ ushort f2bf(float f) {
  uint u = __float_as_uint(f);
  u += 0x7fff + ((u >> 16) & 1);   // RNE
  return (ushort)(u >> 16);
}

__device__ __forceinline__ void gload16(const ushort* g, ushort* l) {
  __builtin_amdgcn_global_load_lds(
      (const __attribute__((address_space(1))) uint*)(const void*)g,
      (__attribute__((address_space(3))) uint*)(void*)l, 16, 0, 0);
}

__device__ __forceinline__ uint cvtpk(float lo, float hi_) {
  uint r;
  asm("v_cvt_pk_bf16_f32 %0, %1, %2" : "=v"(r) : "v"(lo), "v"(hi_));
  return r;
}
__device__ __forceinline__ void pswap(uint &a, uint &b) {
  asm("v_permlane32_swap_b32 %0, %1" : "+v"(a), "+v"(b));
}

// ---------------------------------------------------------------------------
// GEMM core: C[M=4096,N=1024] = A[fp32] @ B[fp32,N-major]^T + bias.
// Tile 64(M) x 128(N), BK=32, 8 waves (2M x 4N), double-buffered LDS.
// A and B converted fp32->bf16 during reg-staging (per-lane ds_write, immune
// to the global_load_lds wave-exec hazard). XOR chunk swizzle write+read.
// MODE 0: fp32 row-major; 1: bf16 [bh][q][d]; 2: bf16 [bh][d][k].
// ---------------------------------------------------------------------------
template<int MODE>
__device__ __forceinline__ void gemm_core(
    const float* __restrict__ A, const float* __restrict__ Bw,
    const float* __restrict__ bias, float* __restrict__ Cf,
    ushort* __restrict__ Cb, int tile,
    ushort (*As)[2048], ushort (*Bs)[4096])
{
  const int tid  = threadIdx.x;
  const int lane = tid & 63;
  const int w    = tid >> 6;
  const int g    = lane >> 4;
  const int lc   = lane & 15;
  const int wr   = w >> 2;      // 0..1 (M)
  const int wc   = w & 3;       // 0..3 (N)
  const int row0 = (tile >> 3) * 64;
  const int col0 = (tile & 7) * 128;

  // staging slots: B 128 rows x 4 chunks (all 512 thr); A 64 x 4 (tid<256)
  const int sr  = tid >> 2;
  const int sc_ = tid & 3;
  const int wofs = sr*32 + (sc_ ^ ((sr >> 1) & 3))*8;   // shorts
  const float* pA = A  + (size_t)(row0 + sr) * HIDc + sc_*8;  // valid tid<256
  const float* pB = Bw + (size_t)(col0 + sr) * HIDc + sc_*8;

  int aoff[2], boff[2];
  #pragma unroll
  for (int mi = 0; mi < 2; ++mi) {
    int r = wr*32 + mi*16 + lc;
    aoff[mi] = r*32 + (g ^ ((r >> 1) & 3)) * 8;
  }
  #pragma unroll
  for (int ni = 0; ni < 2; ++ni) {
    int r = wc*32 + ni*16 + lc;
    boff[ni] = r*32 + (g ^ ((r >> 1) & 3)) * 8;
  }

  f32x4 acc[2][2];
  #pragma unroll
  for (int mi = 0; mi < 2; ++mi)
    #pragma unroll
    for (int ni = 0; ni < 2; ++ni) acc[mi][ni] = (f32x4){0.f,0.f,0.f,0.f};

  float4 a0, a1, b0, b1;
  auto ld = [&](int ko) {
    b0 = *(const float4*)(pB + ko);
    b1 = *(const float4*)(pB + ko + 4);
    if (tid < 256) {
      a0 = *(const float4*)(pA + ko);
      a1 = *(const float4*)(pA + ko + 4);
    }
  };
  auto wrbuf = [&](int bi) {
    ushort tb[8] = { f2bf(b0.x), f2bf(b0.y), f2bf(b0.z), f2bf(b0.w),
                     f2bf(b1.x), f2bf(b1.y), f2bf(b1.z), f2bf(b1.w) };
    *(uint4*)&Bs[bi][wofs] = *(uint4*)tb;
    if (tid < 256) {
      ushort ta[8] = { f2bf(a0.x), f2bf(a0.y), f2bf(a0.z), f2bf(a0.w),
                       f2bf(a1.x), f2bf(a1.y), f2bf(a1.z), f2bf(a1.w) };
      *(uint4*)&As[bi][wofs] = *(uint4*)ta;
    }
  };

  ld(0); wrbuf(0);
  __syncthreads();

  for (int t = 0; t < 32; ++t) {
    if (t < 31) ld((t + 1) * 32);
    const ushort* as = As[t & 1];
    const ushort* bs = Bs[t & 1];
    bf16x8 af[2], bfr[2];
    #pragma unroll
    for (int mi = 0; mi < 2; ++mi) af[mi] = *(const bf16x8*)&as[aoff[mi]];
    #pragma unroll
    for (int ni = 0; ni < 2; ++ni) bfr[ni] = *(const bf16x8*)&bs[boff[ni]];
    #pragma unroll
    for (int mi = 0; mi < 2; ++mi)
      #pragma unroll
      for (int ni = 0; ni < 2; ++ni)
        acc[mi][ni] = __builtin_amdgcn_mfma_f32_16x16x32_bf16(af[mi], bfr[ni], acc[mi][ni], 0, 0, 0);
    if (t < 31) wrbuf((t + 1) & 1);
    __syncthreads();
  }

  const int colbase = col0 + wc*32;
  if (MODE == 0) {
    #pragma unroll
    for (int mi = 0; mi < 2; ++mi) {
      int row = row0 + wr*32 + mi*16 + 4*g;
      #pragma unroll
      for (int ni = 0; ni < 2; ++ni) {
        int col = colbase + ni*16 + lc;
        float bb = bias[col];
        #pragma unroll
        for (int reg = 0; reg < 4; ++reg)
          Cf[(size_t)(row + reg) * HIDc + col] = acc[mi][ni][reg] + bb;
      }
    }
  } else if (MODE == 1) {
    #pragma unroll
    for (int mi = 0; mi < 2; ++mi) {
      int row = row0 + wr*32 + mi*16 + 4*g;
      int b = row >> 11, qq = row & 2047;
      #pragma unroll
      for (int ni = 0; ni < 2; ++ni) {
        int col = colbase + ni*16 + lc;
        int h = col >> 6, d = col & 63;
        float bb = bias[col];
        size_t base = (((size_t)b*Hc + h)*Lc + qq)*HDc + d;
        #pragma unroll
        for (int reg = 0; reg < 4; ++reg)
          Cb[base + (size_t)reg*HDc] = f2bf(acc[mi][ni][reg] + bb);
      }
    }
  } else {
    #pragma unroll
    for (int mi = 0; mi < 2; ++mi) {
      int row = row0 + wr*32 + mi*16 + 4*g;
      int b = row >> 11, kk = row & 2047;
      #pragma unroll
      for (int ni = 0; ni < 2; ++ni) {
        int col = colbase + ni*16 + lc;
        int h = col >> 6, d = col & 63;
        float bb = bias[col];
        ushort t4[4];
        #pragma unroll
        for (int reg = 0; reg < 4; ++reg) t4[reg] = f2bf(acc[mi][ni][reg] + bb);
        *(uint2*)&Cb[(((size_t)b*Hc + h)*HDc + d)*Lc + kk] = *(uint2*)t4;
      }
    }
  }
}

__global__ __launch_bounds__(512)
void gemm_fused(const float* __restrict__ q, const float* __restrict__ k,
                const float* __restrict__ v,
                const float* __restrict__ Wq, const float* __restrict__ Wk,
                const float* __restrict__ Wv,
                const float* __restrict__ bq, const float* __restrict__ bk,
                const float* __restrict__ bv,
                ushort* Qc, ushort* Kc, ushort* Vt)
{
  __shared__ ushort As[2][2048];
  __shared__ ushort Bs[2][4096];
  int gi   = blockIdx.x >> 9;
  int tile = blockIdx.x & 511;
  if (gi == 0)      gemm_core<1>(q, Wq, bq, nullptr, Qc, tile, As, Bs);
  else if (gi == 1) gemm_core<1>(k, Wk, bk, nullptr, Kc, tile, As, Bs);
  else              gemm_core<2>(v, Wv, bv, nullptr, Vt, tile, As, Bs);
}

__global__ __launch_bounds__(512)
void gemm_out(const float* __restrict__ X, const float* __restrict__ Wo,
              const float* __restrict__ bo, float* __restrict__ out)
{
  __shared__ ushort As[2][2048];
  __shared__ ushort Bs[2][4096];
  gemm_core<0>(X, Wo, bo, out, nullptr, blockIdx.x, As, Bs);
}

// ---------------------------------------------------------------------------
// Swapped-QK^T 32x32 MFMA flash attention with Shaw relative positions.
// KVBLK=32, 2 waves/block (QBLK=64), LDS 18.4 KB.
// __launch_bounds__(128) ONLY — R6-R8's ",4" min-waves hint forced the
// allocator to 64 VGPRs and spilled the 32-reg accumulator to scratch
// (R8: VALUBusy 42->16%, dur 98->200us). At the natural ~108 VGPRs the HW
// already gives 4 waves/SIMD = 8 blocks/CU with this LDS footprint.
// Staging: every global_load_lds issued under FULL-wave exec (wave-uniform
// widx selector; gload_lds LDS-writes don't follow exec masks - R6/R7 bug).
// Per buffer: V [64 d][pitch 40] = 320 chunks (ch4 = pad), then K
// [32 k][pitch 64] = 256 chunks, XOR chunk swizzle (source + read side).
// Single 32-k group per tile; exp2-folded softmax (no max; scores bounded);
// Shaw region sums per-lane; P->A via cvt_pk + permlane32_swap;
// epilogue per-q scalars broadcast via __shfl. X written fp32.
// ---------------------------------------------------------------------------
__global__ __launch_bounds__(128)
void attn_mfma32(const ushort* __restrict__ Qc, const ushort* __restrict__ Kc,
                 const ushort* __restrict__ Vt, const float* __restrict__ relk,
                 const float* __restrict__ relv, float* __restrict__ X)
{
  __shared__ ushort KVs[2][4608];      // per buf: V 64x40 | K 32x64(swz)

  const int tid  = threadIdx.x;
  const int w    = tid >> 6;
  const int lane = tid & 63;
  const int lq   = lane & 31;
  const int hi   = lane >> 5;

  // XCD swizzle (1024 blocks = 8 x 128)
  const int swz  = (blockIdx.x & 7) * 128 + (blockIdx.x >> 3);
  const int qblk = swz & 31;
  const int bh   = swz >> 5;
  const int b    = bh >> 4;
  const int h    = bh & 15;
  const int qw   = qblk*64 + w*32;
  const int qabs = qw + lq;

  constexpr float C2 = 0.72134752f;    // 0.5 * log2(e)

  const ushort* Kbh = Kc + (size_t)bh*Lc*HDc;
  const ushort* Vbh = Vt + (size_t)bh*HDc*Lc;

  // Q B-fragments (col=q=lq), k-slice d = 16s + 8hi + j
  bf16x8 qf[4];
  const ushort* qbase = Qc + ((size_t)bh*Lc + qabs)*HDc + 8*hi;
  #pragma unroll
  for (int s = 0; s < 4; ++s) qf[s] = *(const bf16x8*)(qbase + 16*s);

  // dq[bucket] = Q . relk[bucket] via one 32x32 mfma chain (A=relk rows)
  f32x16 dc;
  #pragma unroll
  for (int i = 0; i < 16; ++i) dc[i] = 0.f;
  #pragma unroll
  for (int s = 0; s < 4; ++s) {
    union { ushort u[8]; bf16x8 v; } rf;
    #pragma unroll
    for (int j = 0; j < 8; ++j) rf.u[j] = 0;
    if (lq < 5) {
      #pragma unroll
      for (int j = 0; j < 8; ++j) rf.u[j] = f2bf(relk[lq*HDc + 16*s + 8*hi + j]);
    }
    dc = __builtin_amdgcn_mfma_f32_32x32x16_bf16(rf.v, qf[s], dc, 0, 0, 0);
  }
  float o0 = __shfl_xor(dc[0], 32), o1 = __shfl_xor(dc[1], 32),
        o2 = __shfl_xor(dc[2], 32), o3 = __shfl_xor(dc[3], 32);
  float dqh0, dqh1, dqh2, dqh3, dqh4;
  if (hi == 0) { dqh0 = dc[0]; dqh1 = dc[1]; dqh2 = dc[2]; dqh3 = dc[3]; dqh4 = o0; }
  else         { dqh0 = o0;    dqh1 = o1;    dqh2 = o2;    dqh3 = o3;    dqh4 = dc[0]; }
  dqh0 *= C2; dqh1 *= C2; dqh2 *= C2; dqh3 *= C2; dqh4 *= C2;

  f32x16 acc0, acc1;
  #pragma unroll
  for (int i = 0; i < 16; ++i) { acc0[i] = 0.f; acc1[i] = 0.f; }
  float lsum = 0.f, llo = 0.f, e1 = 0.f, e2 = 0.f, e3 = 0.f;

  // stage one 32-k tile; 9 full-wave loads selected by wave-uniform widx.
  // V chunk vc: row=vc/5 (d), ch=vc%5 (ch4=pad reads next-k, in-bounds of ws).
  // K chunk kc: row=kc>>3 (k), physical chunk pch=kc&7 holds global chunk
  // pch^(row&7); LDS dest linear at (320+kc)*8 shorts.
  auto stage = [&](ushort* dst, int k0) {
    #pragma unroll
    for (int seg = 0; seg < 5; ++seg) {
      int widx = seg*2 + w;             // wave-uniform 0..9
      if (widx < 5) {
        int vc = widx*64 + lane;
        int row = vc/5, ch = vc - row*5;
        gload16(Vbh + (size_t)row*Lc + k0 + ch*8, dst + vc*8);
      } else if (widx < 9) {
        int kc = (widx - 5)*64 + lane;
        int row = kc >> 3, pch = kc & 7;
        int gch = pch ^ (row & 7);
        gload16(Kbh + (size_t)(k0 + row)*HDc + gch*8, dst + (320 + kc)*8);
      }
    }
  };

  stage(KVs[0], 0);
  __syncthreads();

  for (int t = 0; t < Lc/32; ++t) {
    const ushort* vb_ = KVs[t & 1];
    const ushort* kb_ = vb_ + 2560;
    if (t + 1 < Lc/32) stage(KVs[(t+1) & 1], (t+1)*32);
    const int kb = t*32;

    // K fragments (swizzled read), QK^T (C rows = k, cols = q)
    bf16x8 kfa[4];
    #pragma unroll
    for (int s = 0; s < 4; ++s)
      kfa[s] = *(const bf16x8*)&kb_[lq*64 + ((2*s + hi) ^ (lq & 7))*8];
    f32x16 c0;
    #pragma unroll
    for (int i = 0; i < 16; ++i) c0[i] = 0.f;
    __builtin_amdgcn_s_setprio(1);
    #pragma unroll
    for (int s = 0; s < 4; ++s)
      c0 = __builtin_amdgcn_mfma_f32_32x32x16_bf16(kfa[s], qf[s], c0, 0, 0, 0);
    __builtin_amdgcn_s_setprio(0);

    // V fragments (B operand: col=d, k elements)
    bf16x8 vf00 = *(const bf16x8*)&vb_[lq*40      + hi*8];
    bf16x8 vf01 = *(const bf16x8*)&vb_[(32+lq)*40 + hi*8];
    bf16x8 vf10 = *(const bf16x8*)&vb_[lq*40      + (2+hi)*8];
    bf16x8 vf11 = *(const bf16x8*)&vb_[(32+lq)*40 + (2+hi)*8];

    // softmax (no max subtraction; scores bounded), region sums, pack
    uint pk[8];
    const bool allhi = (kb >= qw + 33);
    const bool alllo = (kb + 33 <= qw);
    if (allhi | alllo) {
      const float dq = allhi ? dqh4 : dqh0;
      float gs = 0.f;
      #pragma unroll
      for (int jj = 0; jj < 8; ++jj) {
        float pa = __builtin_amdgcn_exp2f(__builtin_fmaf(c0[2*jj],   C2, dq));
        float pb = __builtin_amdgcn_exp2f(__builtin_fmaf(c0[2*jj+1], C2, dq));
        gs += pa + pb;
        pk[jj] = cvtpk(pa, pb);
      }
      lsum += gs;
      if (alllo) llo += gs;
    } else {
      int bnum = kb + 4*hi - qabs;
      #pragma unroll
      for (int jj = 0; jj < 8; ++jj) {
        int r0 = 2*jj;
        int d0 = bnum + ((r0 & 3) + 8*(r0 >> 2));
        int d1 = d0 + 1;
        float dqa = d0 <= -2 ? dqh0 : (d0 >= 2 ? dqh4 :
                    (d0 == -1 ? dqh1 : (d0 == 0 ? dqh2 : dqh3)));
        float dqb = d1 <= -2 ? dqh0 : (d1 >= 2 ? dqh4 :
                    (d1 == -1 ? dqh1 : (d1 == 0 ? dqh2 : dqh3)));
        float pa = __builtin_amdgcn_exp2f(__builtin_fmaf(c0[r0],   C2, dqa));
        float pb = __builtin_amdgcn_exp2f(__builtin_fmaf(c0[r0+1], C2, dqb));
        lsum += pa + pb;
        llo += (d0 <= -2 ? pa : 0.f) + (d1 <= -2 ? pb : 0.f);
        e1  += (d0 == -1 ? pa : 0.f) + (d1 == -1 ? pb : 0.f);
        e2  += (d0 ==  0 ? pa : 0.f) + (d1 ==  0 ? pb : 0.f);
        e3  += (d0 ==  1 ? pa : 0.f) + (d1 ==  1 ? pb : 0.f);
        pk[jj] = cvtpk(pa, pb);
      }
    }

    // PV (A = P via permlane redistribution)
    uint X0 = pk[0], X1 = pk[1], Y0 = pk[2], Y1 = pk[3];
    pswap(X0, Y0); pswap(X1, Y1);
    union { uint u[4]; bf16x8 v; } aw0;
    aw0.u[0] = X0; aw0.u[1] = X1; aw0.u[2] = Y0; aw0.u[3] = Y1;
    X0 = pk[4]; X1 = pk[5]; Y0 = pk[6]; Y1 = pk[7];
    pswap(X0, Y0); pswap(X1, Y1);
    union { uint u[4]; bf16x8 v; } aw1;
    aw1.u[0] = X0; aw1.u[1] = X1; aw1.u[2] = Y0; aw1.u[3] = Y1;
    __builtin_amdgcn_s_setprio(1);
    acc0 = __builtin_amdgcn_mfma_f32_32x32x16_bf16(aw0.v, vf00, acc0, 0, 0, 0);
    acc1 = __builtin_amdgcn_mfma_f32_32x32x16_bf16(aw0.v, vf01, acc1, 0, 0, 0);
    acc0 = __builtin_amdgcn_mfma_f32_32x32x16_bf16(aw1.v, vf10, acc0, 0, 0, 0);
    acc1 = __builtin_amdgcn_mfma_f32_32x32x16_bf16(aw1.v, vf11, acc1, 0, 0, 0);
    __builtin_amdgcn_s_setprio(0);
    __syncthreads();
  }

  // epilogue: combine hi-halves (all sums linear), shfl-broadcast per-q scalars
  float Ls = lsum + __shfl_xor(lsum, 32);
  float Lo = llo  + __shfl_xor(llo, 32);
  float E1 = e1   + __shfl_xor(e1, 32);
  float E2 = e2   + __shfl_xor(e2, 32);
  float E3 = e3   + __shfl_xor(e3, 32);
  float inv = 1.f / Ls;
  float s0v = Lo*inv, s1v = E1*inv, s2v = E2*inv, s3v = E3*inv;
  float s4v = 1.f - s0v - s1v - s2v - s3v;

  float rvv[5][2];
  #pragma unroll
  for (int r = 0; r < 5; ++r) {
    rvv[r][0] = relv[r*HDc + lq];
    rvv[r][1] = relv[r*HDc + 32 + lq];
  }
  #pragma unroll
  for (int r = 0; r < 16; ++r) {
    int qloc = ((r & 3) + 8*(r >> 2)) + 4*hi;
    float iv = __shfl(inv, qloc);
    float t0 = __shfl(s0v, qloc);
    float t1 = __shfl(s1v, qloc);
    float t2 = __shfl(s2v, qloc);
    float t3 = __shfl(s3v, qloc);
    float t4 = __shfl(s4v, qloc);
    size_t rowb = ((size_t)(b*Lc + qw + qloc))*HIDc + h*HDc;
    X[rowb + lq]      = acc0[r]*iv + t0*rvv[0][0] + t1*rvv[1][0] + t2*rvv[2][0]
                      + t3*rvv[3][0] + t4*rvv[4][0];
    X[rowb + 32 + lq] = acc1[r]*iv + t0*rvv[0][1] + t1*rvv[1][1] + t2*rvv[2][1]
                      + t3*rvv[3][1] + t4*rvv[4][1];
  }
}

// ---------------------------------------------------------------------------
extern "C" void kernel_launch(void* const* d_in, const int* in_sizes, int n_in,
                              void* d_out, int out_size, void* d_ws, size_t ws_size,
                              hipStream_t stream) {
  const float* query = (const float*)d_in[0];
  const float* key   = (const float*)d_in[1];
  const float* value = (const float*)d_in[2];
  const float* Wq    = (const float*)d_in[3];
  const float* bq    = (const float*)d_in[4];
  const float* Wk    = (const float*)d_in[5];
  const float* bk    = (const float*)d_in[6];
  const float* Wv    = (const float*)d_in[7];
  const float* bv    = (const float*)d_in[8];
  const float* Wo    = (const float*)d_in[9];
  const float* bo    = (const float*)d_in[10];
  const float* relk  = (const float*)d_in[11];
  const float* relv  = (const float*)d_in[12];
  float* out = (float*)d_out;

  // ws: Qc, Kc, Vt (bf16, 8.39 MB each) then X (fp32, 16.78 MB) = 41.9 MB.
  // V pad-chunk reads may run a few elements past Vt (into Xb) - in-bounds.
  size_t S = (size_t)Bc * Hc * Lc * HDc;   // 4.19M elems
  ushort* Qc = (ushort*)d_ws;
  ushort* Kc = Qc + S;
  ushort* Vt = Kc + S;
  float*  Xb = (float*)(Vt + S);

  gemm_fused<<<3*512, 512, 0, stream>>>(query, key, value, Wq, Wk, Wv,
                                        bq, bk, bv, Qc, Kc, Vt);

  attn_mfma32<<<Bc * Hc * (Lc / 64), 128, 0, stream>>>(Qc, Kc, Vt, relk, relv, Xb);

  gemm_out<<<512, 512, 0, stream>>>(Xb, Wo, bo, out);
}